// Round 1
// baseline (640.283 us; speedup 1.0000x reference)
//
#include <hip/hip_runtime.h>
#include <hip/hip_bf16.h>
#include <math.h>

// Problem constants
#define DD 256
#define TT 4096
#define NBATCH 8
#define BTOK 32768            // NBATCH*TT tokens
#define EPSF 1e-7f

// ---------------- helpers ----------------
__device__ __forceinline__ float softplusf(float x) {
  return fmaxf(x, 0.f) + log1pf(expf(-fabsf(x)));
}
__device__ __forceinline__ float bf2f(unsigned short u) {
  union { unsigned int i; float f; } v; v.i = ((unsigned int)u) << 16; return v.f;
}
__device__ __forceinline__ unsigned short f2bf(float f) {  // RTNE
  union { float f; unsigned int i; } v; v.f = f;
  unsigned int x = v.i;
  unsigned int lsb = (x >> 16) & 1u;
  x += 0x7fffu + lsb;
  return (unsigned short)(x >> 16);
}
// decay = exp(are + i*aim); forcing = (decay-1)/(exp_arg + eps*sign(re+eps))
__device__ __forceinline__ void decay_forcing(float are, float aim,
    float& dre, float& dim, float& fre, float& fim) {
  float e = expf(are);
  float s, c; sincosf(aim, &s, &c);
  dre = e * c; dim = e * s;
  float sg = (are + EPSF >= 0.f) ? 1.f : -1.f;
  float denr = are + EPSF * sg;
  float deni = aim;
  float inv = 1.f / (denr * denr + deni * deni);
  float nr = dre - 1.f, ni = dim;
  fre = (nr * denr + ni * deni) * inv;
  fim = (ni * denr - nr * deni) * inv;
}

// ---------------- K1: x_in GEMM (M=32768, N=256 complex, K=256) + forcing epilogue ----------------
// Stages X_scan = (x @ Win[0:256,0:256]^T + i * x @ Win[256:512,0:256]^T + bias) * forcing  as bf16.
__global__ __launch_bounds__(256) void k1_gemm_in(
    const float* __restrict__ x, const float* __restrict__ Win,
    const float* __restrict__ bin, const float* __restrict__ dts,
    const float* __restrict__ decr, const float* __restrict__ deci,
    unsigned short* __restrict__ Xre, unsigned short* __restrict__ Xim)
{
  __shared__ __align__(16) float As[16][64];
  __shared__ __align__(16) float Wr[16][64];
  __shared__ __align__(16) float Wi[16][64];
  const int mt = blockIdx.x & 511;        // 512 token tiles of 64
  const int nt = blockIdx.x >> 9;         // 4 col tiles of 64
  const int tok0 = mt * 64;
  const int col0 = nt * 64;
  const int tid = threadIdx.x;
  const int tm = tid & 15, tn = tid >> 4; // 16x16 thread grid, 4x4 microtile
  const int lm = tid >> 2;                // load row 0..63
  const int lk = (tid & 3) << 2;          // load k offset 0,4,8,12
  float accr[4][4] = {{0.f}};
  float acci[4][4] = {{0.f}};
  for (int k0 = 0; k0 < 256; k0 += 16) {
    float4 ga = *reinterpret_cast<const float4*>(&x[(size_t)(tok0 + lm) * 256 + k0 + lk]);
    float4 gr = *reinterpret_cast<const float4*>(&Win[(size_t)(col0 + lm) * 512 + k0 + lk]);
    float4 gi = *reinterpret_cast<const float4*>(&Win[(size_t)(col0 + lm + 256) * 512 + k0 + lk]);
    __syncthreads();
    As[lk + 0][lm] = ga.x; As[lk + 1][lm] = ga.y; As[lk + 2][lm] = ga.z; As[lk + 3][lm] = ga.w;
    Wr[lk + 0][lm] = gr.x; Wr[lk + 1][lm] = gr.y; Wr[lk + 2][lm] = gr.z; Wr[lk + 3][lm] = gr.w;
    Wi[lk + 0][lm] = gi.x; Wi[lk + 1][lm] = gi.y; Wi[lk + 2][lm] = gi.z; Wi[lk + 3][lm] = gi.w;
    __syncthreads();
#pragma unroll
    for (int k = 0; k < 16; ++k) {
      float a[4], br[4], bi[4];
      *reinterpret_cast<float4*>(a)  = *reinterpret_cast<const float4*>(&As[k][tm * 4]);
      *reinterpret_cast<float4*>(br) = *reinterpret_cast<const float4*>(&Wr[k][tn * 4]);
      *reinterpret_cast<float4*>(bi) = *reinterpret_cast<const float4*>(&Wi[k][tn * 4]);
#pragma unroll
      for (int i = 0; i < 4; ++i)
#pragma unroll
        for (int j = 0; j < 4; ++j) {
          accr[i][j] = fmaf(a[i], br[j], accr[i][j]);
          acci[i][j] = fmaf(a[i], bi[j], acci[i][j]);
        }
    }
  }
  const int tokb = tok0 + tm * 4;
  const int colb = col0 + tn * 4;
  float dtv[4], nre[4], dimc[4], b0[4], b1[4];
#pragma unroll
  for (int i = 0; i < 4; ++i) dtv[i] = dts[tokb + i];
#pragma unroll
  for (int j = 0; j < 4; ++j) {
    int d = colb + j;
    nre[j] = -softplusf(decr[d]);
    dimc[j] = deci[d];
    b0[j] = bin[d]; b1[j] = bin[d + 256];
  }
#pragma unroll
  for (int i = 0; i < 4; ++i) {
    unsigned short vr[4], vi[4];
#pragma unroll
    for (int j = 0; j < 4; ++j) {
      float xr = accr[i][j] + b0[j];
      float xi = acci[i][j] + b1[j];
      float are = nre[j] * dtv[i], aim = dimc[j] * dtv[i];
      float dr, dm, fr, fm;
      decay_forcing(are, aim, dr, dm, fr, fm);
      vr[j] = f2bf(xr * fr - xi * fm);
      vi[j] = f2bf(xr * fm + xi * fr);
    }
    ushort4 sr, si;
    sr.x = vr[0]; sr.y = vr[1]; sr.z = vr[2]; sr.w = vr[3];
    si.x = vi[0]; si.y = vi[1]; si.z = vi[2]; si.w = vi[3];
    size_t idx = (size_t)(tokb + i) * DD + colb;
    *reinterpret_cast<ushort4*>(&Xre[idx]) = sr;
    *reinterpret_cast<ushort4*>(&Xim[idx]) = si;
  }
}

// ---------------- K2a: per-chunk scan operators (A,B) over chunks of 64 steps ----------------
__global__ __launch_bounds__(256) void k2a_chunk(
    const unsigned short* __restrict__ Xre, const unsigned short* __restrict__ Xim,
    const float* __restrict__ dts, const float* __restrict__ decr, const float* __restrict__ deci,
    float4* __restrict__ ops)
{
  const int b = blockIdx.x >> 6;   // 8 batches
  const int c = blockIdx.x & 63;   // 64 chunks
  const int d = threadIdx.x;       // 256 channels
  __shared__ float sdt[64];
  if (threadIdx.x < 64) sdt[threadIdx.x] = dts[b * TT + c * 64 + threadIdx.x];
  float nre = -softplusf(decr[d]);
  float di = deci[d];
  __syncthreads();
  float Ar = 1.f, Ai = 0.f, Br2 = 0.f, Bi2 = 0.f;
  size_t base = (size_t)(b * TT + c * 64) * DD + d;
  for (int i = 0; i < 64; ++i) {
    float dt = sdt[i];
    float are = nre * dt, aim = di * dt;
    float e = expf(are); float s, cs; sincosf(aim, &s, &cs);
    float ar = e * cs, ai2 = e * s;
    float xr = bf2f(Xre[base]), xi = bf2f(Xim[base]);
    base += DD;
    float nAr = Ar * ar - Ai * ai2;
    float nAi = Ar * ai2 + Ai * ar;
    Ar = nAr; Ai = nAi;
    float nBr = Br2 * ar - Bi2 * ai2 + xr;
    float nBi = Br2 * ai2 + Bi2 * ar + xi;
    Br2 = nBr; Bi2 = nBi;
  }
  ops[(size_t)(b * 64 + c) * DD + d] = make_float4(Ar, Ai, Br2, Bi2);
}

// ---------------- K2b: carry scan across 64 chunks per channel ----------------
__global__ __launch_bounds__(256) void k2b_carry(
    const float4* __restrict__ ops, float2* __restrict__ hin)
{
  const int b = blockIdx.x;
  const int d = threadIdx.x;
  float hr = 0.f, hi = 0.f;
  for (int c = 0; c < 64; ++c) {
    size_t idx = (size_t)(b * 64 + c) * DD + d;
    hin[idx] = make_float2(hr, hi);
    float4 o = ops[idx];
    float nr = o.x * hr - o.y * hi + o.z;
    float ni = o.x * hi + o.y * hr + o.w;
    hr = nr; hi = ni;
  }
}

// ---------------- K2c: apply — re-scan each chunk from its incoming carry; store flux bf16 ----------------
__global__ __launch_bounds__(256) void k2c_apply(
    const unsigned short* __restrict__ Xre, const unsigned short* __restrict__ Xim,
    const float* __restrict__ dts, const float* __restrict__ decr, const float* __restrict__ deci,
    const float2* __restrict__ hin,
    unsigned short* __restrict__ Fre, unsigned short* __restrict__ Fim)
{
  const int b = blockIdx.x >> 6;
  const int c = blockIdx.x & 63;
  const int d = threadIdx.x;
  __shared__ float sdt[64];
  if (threadIdx.x < 64) sdt[threadIdx.x] = dts[b * TT + c * 64 + threadIdx.x];
  float nre = -softplusf(decr[d]);
  float di = deci[d];
  __syncthreads();
  float2 h = hin[(size_t)(b * 64 + c) * DD + d];
  float hr = h.x, hi = h.y;
  size_t base = (size_t)(b * TT + c * 64) * DD + d;
  for (int i = 0; i < 64; ++i) {
    float dt = sdt[i];
    float are = nre * dt, aim = di * dt;
    float e = expf(are); float s, cs; sincosf(aim, &s, &cs);
    float ar = e * cs, ai2 = e * s;
    float xr = bf2f(Xre[base]), xi = bf2f(Xim[base]);
    float nr = ar * hr - ai2 * hi + xr;
    float ni = ar * hi + ai2 * hr + xi;
    hr = nr; hi = ni;
    Fre[base] = f2bf(hr); Fim[base] = f2bf(hi);
    base += DD;
  }
}

// ---------------- K3: output GEMM (M=32768, N=768 = 512 src + 256 gate, K=512) ----------------
__global__ __launch_bounds__(256) void k3_gemm_out(
    const unsigned short* __restrict__ Fre, const unsigned short* __restrict__ Fim,
    const float* __restrict__ Wout, const float* __restrict__ bout,
    const float* __restrict__ Wgate, const float* __restrict__ bgate,
    float* __restrict__ out)
{
  __shared__ __align__(16) float As[16][64];
  __shared__ __align__(16) float Bs[16][64];
  const int mt = blockIdx.x & 511;   // 512 token tiles
  const int nt = blockIdx.x >> 9;    // 12 col tiles
  const int tok0 = mt * 64;
  const int col0 = nt * 64;
  const int tid = threadIdx.x;
  const int tm = tid & 15, tn = tid >> 4;
  const int lm = tid >> 2;
  const int lk = (tid & 3) << 2;
  const int wrow = col0 + lm;
  const float* wp = (wrow < 512) ? (Wout + (size_t)wrow * 512)
                                 : (Wgate + (size_t)(wrow - 512) * 512);
  float acc[4][4] = {{0.f}};
  for (int k0 = 0; k0 < 512; k0 += 16) {
    const unsigned short* plane = (k0 < 256) ? Fre : Fim;
    int kc = (k0 & 255) + lk;
    ushort4 ua = *reinterpret_cast<const ushort4*>(&plane[(size_t)(tok0 + lm) * DD + kc]);
    float4 gw = *reinterpret_cast<const float4*>(&wp[k0 + lk]);
    __syncthreads();
    As[lk + 0][lm] = bf2f(ua.x); As[lk + 1][lm] = bf2f(ua.y);
    As[lk + 2][lm] = bf2f(ua.z); As[lk + 3][lm] = bf2f(ua.w);
    Bs[lk + 0][lm] = gw.x; Bs[lk + 1][lm] = gw.y; Bs[lk + 2][lm] = gw.z; Bs[lk + 3][lm] = gw.w;
    __syncthreads();
#pragma unroll
    for (int k = 0; k < 16; ++k) {
      float a[4], bw[4];
      *reinterpret_cast<float4*>(a)  = *reinterpret_cast<const float4*>(&As[k][tm * 4]);
      *reinterpret_cast<float4*>(bw) = *reinterpret_cast<const float4*>(&Bs[k][tn * 4]);
#pragma unroll
      for (int i = 0; i < 4; ++i)
#pragma unroll
        for (int j = 0; j < 4; ++j)
          acc[i][j] = fmaf(a[i], bw[j], acc[i][j]);
    }
  }
  const int tokb = tok0 + tm * 4;
  const int colb = col0 + tn * 4;
  if (col0 < 512) {   // src_re / src_im: direct + bias
    float bb[4];
#pragma unroll
    for (int j = 0; j < 4; ++j) bb[j] = bout[colb + j];
#pragma unroll
    for (int i = 0; i < 4; ++i) {
      float4 v;
      v.x = acc[i][0] + bb[0]; v.y = acc[i][1] + bb[1];
      v.z = acc[i][2] + bb[2]; v.w = acc[i][3] + bb[3];
      *reinterpret_cast<float4*>(&out[(size_t)(tokb + i) * 1792 + colb]) = v;
    }
  } else {            // gate: sigmoid then affine to [0.01, 0.99]
    float bb[4];
#pragma unroll
    for (int j = 0; j < 4; ++j) bb[j] = bgate[colb - 512 + j];
#pragma unroll
    for (int i = 0; i < 4; ++i) {
      float t[4];
#pragma unroll
      for (int j = 0; j < 4; ++j) {
        float g = 1.f / (1.f + expf(-(acc[i][j] + bb[j])));
        t[j] = g * 0.98f + 0.01f;
      }
      float4 v; v.x = t[0]; v.y = t[1]; v.z = t[2]; v.w = t[3];
      *reinterpret_cast<float4*>(&out[(size_t)(tokb + i) * 1792 + colb]) = v;
    }
  }
}

// ---------------- K4: decay_p / forcing_p planes (elementwise, depends only on dt & lam_p) ----------------
__global__ __launch_bounds__(256) void k4_prop(
    const float* __restrict__ dts, const float* __restrict__ lre,
    const float* __restrict__ lim, float* __restrict__ out)
{
  const int tok = blockIdx.x;
  const int d = threadIdx.x;
  float dt = dts[tok];
  float are = -softplusf(lre[d]) * dt;
  float aim = lim[d] * dt;
  float dr, dm, fr, fm;
  decay_forcing(are, aim, dr, dm, fr, fm);
  float* o = out + (size_t)tok * 1792 + 768;
  o[d] = dr; o[256 + d] = dm; o[512 + d] = fr; o[768 + d] = fm;
}

// ---------------- launch ----------------
extern "C" void kernel_launch(void* const* d_in, const int* in_sizes, int n_in,
                              void* d_out, int out_size, void* d_ws, size_t ws_size,
                              hipStream_t stream)
{
  const float* x     = (const float*)d_in[0];
  const float* dts   = (const float*)d_in[1];
  const float* decr  = (const float*)d_in[2];
  const float* deci  = (const float*)d_in[3];
  const float* Win   = (const float*)d_in[4];
  const float* bin   = (const float*)d_in[5];
  const float* Wout  = (const float*)d_in[6];
  const float* bout  = (const float*)d_in[7];
  const float* Wgate = (const float*)d_in[8];
  const float* bgate = (const float*)d_in[9];
  const float* lre   = (const float*)d_in[10];
  const float* lim   = (const float*)d_in[11];
  float* out = (float*)d_out;
  char* ws = (char*)d_ws;

  // Workspace layout (~70.3 MB total):
  //   Xre/Xim  : bf16 [BTOK, DD] each (16 MB each)   — X_scan staged
  //   Fre/Fim  : bf16 [BTOK, DD] each (16 MB each)   — flux staged
  //   ops      : float4 [8*64*256] (2 MB)            — chunk operators
  //   hin      : float2 [8*64*256] (1 MB)            — chunk incoming carries
  const size_t PLANE = (size_t)BTOK * DD * sizeof(unsigned short);
  unsigned short* Xre = (unsigned short*)(ws);
  unsigned short* Xim = (unsigned short*)(ws + PLANE);
  unsigned short* Fre = (unsigned short*)(ws + 2 * PLANE);
  unsigned short* Fim = (unsigned short*)(ws + 3 * PLANE);
  float4* ops = (float4*)(ws + 4 * PLANE);
  float2* hin = (float2*)(ws + 4 * PLANE + (size_t)NBATCH * 64 * DD * sizeof(float4));

  k1_gemm_in<<<2048, 256, 0, stream>>>(x, Win, bin, dts, decr, deci, Xre, Xim);
  k2a_chunk<<<512, 256, 0, stream>>>(Xre, Xim, dts, decr, deci, ops);
  k2b_carry<<<8, 256, 0, stream>>>(ops, hin);
  k2c_apply<<<512, 256, 0, stream>>>(Xre, Xim, dts, decr, deci, hin, Fre, Fim);
  k3_gemm_out<<<6144, 256, 0, stream>>>(Fre, Fim, Wout, bout, Wgate, bgate, out);
  k4_prop<<<32768, 256, 0, stream>>>(dts, lre, lim, out);
}

// Round 3
// 216.105 us; speedup vs baseline: 2.9628x; 2.9628x over previous
//
#include <hip/hip_runtime.h>
#include <math.h>

// Problem constants
#define DD 256
#define TT 4096
#define NBATCH 8
#define BTOK 32768            // NBATCH*TT tokens
#define EPSF 1e-7f

typedef __attribute__((ext_vector_type(4))) float f32x4;
typedef __attribute__((ext_vector_type(8))) short bf16x8;

// ---------------- helpers ----------------
__device__ __forceinline__ float softplusf(float x) {
  return fmaxf(x, 0.f) + log1pf(expf(-fabsf(x)));
}
__device__ __forceinline__ float bf2f(unsigned short u) {
  union { unsigned int i; float f; } v; v.i = ((unsigned int)u) << 16; return v.f;
}
__device__ __forceinline__ unsigned short f2bf(float f) {  // RTNE
  union { float f; unsigned int i; } v; v.f = f;
  unsigned int x = v.i;
  unsigned int lsb = (x >> 16) & 1u;
  x += 0x7fffu + lsb;
  return (unsigned short)(x >> 16);
}
// decay = exp(are + i*aim); forcing = (decay-1)/(exp_arg + eps*sign(re+eps))
__device__ __forceinline__ void decay_forcing(float are, float aim,
    float& dre, float& dim, float& fre, float& fim) {
  float e = expf(are);
  float s, c; sincosf(aim, &s, &c);
  dre = e * c; dim = e * s;
  float sg = (are + EPSF >= 0.f) ? 1.f : -1.f;
  float denr = are + EPSF * sg;
  float deni = aim;
  float inv = 1.f / (denr * denr + deni * deni);
  float nr = dre - 1.f, ni = dim;
  fre = (nr * denr + ni * deni) * inv;
  fim = (ni * denr - nr * deni) * inv;
}
// async 16B global->LDS (linear dest: wave-uniform base + lane*16)
__device__ __forceinline__ void gl_lds16(const void* g, void* l) {
  __builtin_amdgcn_global_load_lds(
      (const __attribute__((address_space(1))) unsigned int*)g,
      (__attribute__((address_space(3))) unsigned int*)l, 16, 0, 0);
}

// ---------------- prep: fp32 -> bf16 conversions ----------------
// x has BTOK*256 = 8,388,608 floats; each thread converts 4 -> grid 8192.
__global__ __launch_bounds__(256) void xcvt(const float* __restrict__ x,
                                            unsigned short* __restrict__ Xb) {
  size_t i = ((size_t)blockIdx.x * 256 + threadIdx.x) * 4;
  float4 v = *reinterpret_cast<const float4*>(&x[i]);
  ushort4 u;
  u.x = f2bf(v.x); u.y = f2bf(v.y); u.z = f2bf(v.z); u.w = f2bf(v.w);
  *reinterpret_cast<ushort4*>(&Xb[i]) = u;
}

// Pack Win (only k<256 matters; imag input is zero) into [512][256] bf16 with
// re/im rows interleaved in 16-wide groups: row p: g=p>>5, r=p&31,
// src = (r<16) ? g*16+r : 256 + g*16 + (r-16).
__global__ __launch_bounds__(256) void wpack1(const float* __restrict__ Win,
                                              unsigned short* __restrict__ Wp) {
  const int p = blockIdx.x;          // 0..511
  const int k = threadIdx.x;         // 0..255
  const int g = p >> 5, r = p & 31;
  const int src = (r < 16) ? (g * 16 + r) : (256 + g * 16 + (r - 16));
  Wp[(size_t)p * 256 + k] = f2bf(Win[(size_t)src * 512 + k]);
}

// Pack Wout (512 rows) + Wgate (256 rows) into [768][512] bf16.
__global__ __launch_bounds__(256) void wpack3(const float* __restrict__ Wout,
                                              const float* __restrict__ Wgate,
                                              unsigned short* __restrict__ Wp) {
  const int p = blockIdx.x;          // 0..767
  const float* src = (p < 512) ? (Wout + (size_t)p * 512)
                               : (Wgate + (size_t)(p - 512) * 512);
  Wp[(size_t)p * 512 + threadIdx.x] = f2bf(src[threadIdx.x]);
  Wp[(size_t)p * 512 + threadIdx.x + 256] = f2bf(src[threadIdx.x + 256]);
}

// ---------------- K1: MFMA GEMM (M=32768, K=256, N=512 packed) + forcing epilogue ----------------
__global__ __launch_bounds__(256) void k1_mfma(
    const unsigned short* __restrict__ Xb,   // [BTOK][256] bf16
    const unsigned short* __restrict__ Wp,   // [512][256] bf16 (re/im 16-interleaved)
    const float* __restrict__ bin, const float* __restrict__ dts,
    const float* __restrict__ decr, const float* __restrict__ deci,
    unsigned short* __restrict__ Xre, unsigned short* __restrict__ Xim)
{
  __shared__ __align__(16) unsigned short As[128 * 32];
  __shared__ __align__(16) unsigned short Bs[128 * 32];
  const int bx = blockIdx.x;
  const int mt = bx & 255, nt = bx >> 8;
  const int m0 = mt * 128, n0 = nt * 128;
  const int tid = threadIdx.x;
  const int lane = tid & 63, wid = tid >> 6;
  const int wr = wid >> 1, wc = wid & 1;
  const int l15 = lane & 15, hi8 = (lane >> 4) * 8;
  const int srow = tid >> 2, skof = (tid & 3) * 8;
  f32x4 acc[4][4];
  f32x4 z = {0.f, 0.f, 0.f, 0.f};
#pragma unroll
  for (int i = 0; i < 4; ++i)
#pragma unroll
    for (int j = 0; j < 4; ++j) acc[i][j] = z;

  for (int k0 = 0; k0 < 256; k0 += 32) {
    __syncthreads();
    gl_lds16(&Xb[(size_t)(m0 + srow) * 256 + k0 + skof], &As[tid * 8]);
    gl_lds16(&Xb[(size_t)(m0 + 64 + srow) * 256 + k0 + skof], &As[2048 + tid * 8]);
    gl_lds16(&Wp[(size_t)(n0 + srow) * 256 + k0 + skof], &Bs[tid * 8]);
    gl_lds16(&Wp[(size_t)(n0 + 64 + srow) * 256 + k0 + skof], &Bs[2048 + tid * 8]);
    __syncthreads();
    bf16x8 af[4], bfr[4];
#pragma unroll
    for (int m = 0; m < 4; ++m)
      af[m] = *reinterpret_cast<const bf16x8*>(&As[(wr * 64 + m * 16 + l15) * 32 + hi8]);
#pragma unroll
    for (int n = 0; n < 4; ++n)
      bfr[n] = *reinterpret_cast<const bf16x8*>(&Bs[(wc * 64 + n * 16 + l15) * 32 + hi8]);
#pragma unroll
    for (int m = 0; m < 4; ++m)
#pragma unroll
      for (int n = 0; n < 4; ++n)
        acc[m][n] = __builtin_amdgcn_mfma_f32_16x16x32_bf16(af[m], bfr[n], acc[m][n], 0, 0, 0);
  }

  // epilogue: fragment pair (2*pr, 2*pr+1) = (re, im) for same d in same lane
  const int pbase = n0 + wc * 64;
#pragma unroll
  for (int pr = 0; pr < 2; ++pr) {
    const int d = (pbase >> 1) + pr * 16 + l15;
    const float nre = -softplusf(decr[d]);
    const float di = deci[d];
    const float br = bin[d], bi = bin[d + 256];
#pragma unroll
    for (int m = 0; m < 4; ++m) {
#pragma unroll
      for (int r = 0; r < 4; ++r) {
        const int row = m0 + wr * 64 + m * 16 + (lane >> 4) * 4 + r;
        float xr = acc[m][2 * pr][r] + br;
        float xi = acc[m][2 * pr + 1][r] + bi;
        float dt = dts[row];
        float are = nre * dt, aim = di * dt;
        float dr_, dm_, fr_, fm_;
        decay_forcing(are, aim, dr_, dm_, fr_, fm_);
        Xre[(size_t)row * DD + d] = f2bf(xr * fr_ - xi * fm_);
        Xim[(size_t)row * DD + d] = f2bf(xr * fm_ + xi * fr_);
      }
    }
  }
}

// ---------------- K2a: per-chunk scan operators over chunks of 64 steps ----------------
__global__ __launch_bounds__(256) void k2a_chunk(
    const unsigned short* __restrict__ Xre, const unsigned short* __restrict__ Xim,
    const float* __restrict__ dts, const float* __restrict__ decr, const float* __restrict__ deci,
    float4* __restrict__ ops)
{
  const int b = blockIdx.x >> 6;
  const int c = blockIdx.x & 63;
  const int d = threadIdx.x;
  __shared__ float sdt[64];
  if (threadIdx.x < 64) sdt[threadIdx.x] = dts[b * TT + c * 64 + threadIdx.x];
  float nre = -softplusf(decr[d]);
  float di = deci[d];
  __syncthreads();
  float Ar = 1.f, Ai = 0.f, Br2 = 0.f, Bi2 = 0.f;
  size_t base = (size_t)(b * TT + c * 64) * DD + d;
  for (int i = 0; i < 64; ++i) {
    float dt = sdt[i];
    float are = nre * dt, aim = di * dt;
    float e = expf(are); float s, cs; sincosf(aim, &s, &cs);
    float ar = e * cs, ai2 = e * s;
    float xr = bf2f(Xre[base]), xi = bf2f(Xim[base]);
    base += DD;
    float nAr = Ar * ar - Ai * ai2;
    float nAi = Ar * ai2 + Ai * ar;
    Ar = nAr; Ai = nAi;
    float nBr = Br2 * ar - Bi2 * ai2 + xr;
    float nBi = Br2 * ai2 + Bi2 * ar + xi;
    Br2 = nBr; Bi2 = nBi;
  }
  ops[(size_t)(b * 64 + c) * DD + d] = make_float4(Ar, Ai, Br2, Bi2);
}

// ---------------- K2b: carry scan across 64 chunks per channel ----------------
__global__ __launch_bounds__(256) void k2b_carry(
    const float4* __restrict__ ops, float2* __restrict__ hin)
{
  const int b = blockIdx.x;
  const int d = threadIdx.x;
  float hr = 0.f, hi = 0.f;
  for (int c = 0; c < 64; ++c) {
    size_t idx = (size_t)(b * 64 + c) * DD + d;
    hin[idx] = make_float2(hr, hi);
    float4 o = ops[idx];
    float nr = o.x * hr - o.y * hi + o.z;
    float ni = o.x * hi + o.y * hr + o.w;
    hr = nr; hi = ni;
  }
}

// ---------------- K2c: apply; store flux packed [token][512] bf16 (re | im) ----------------
__global__ __launch_bounds__(256) void k2c_apply(
    const unsigned short* __restrict__ Xre, const unsigned short* __restrict__ Xim,
    const float* __restrict__ dts, const float* __restrict__ decr, const float* __restrict__ deci,
    const float2* __restrict__ hin,
    unsigned short* __restrict__ F)
{
  const int b = blockIdx.x >> 6;
  const int c = blockIdx.x & 63;
  const int d = threadIdx.x;
  __shared__ float sdt[64];
  if (threadIdx.x < 64) sdt[threadIdx.x] = dts[b * TT + c * 64 + threadIdx.x];
  float nre = -softplusf(decr[d]);
  float di = deci[d];
  __syncthreads();
  float2 h = hin[(size_t)(b * 64 + c) * DD + d];
  float hr = h.x, hi = h.y;
  int tok = b * TT + c * 64;
  size_t base = (size_t)tok * DD + d;
  for (int i = 0; i < 64; ++i) {
    float dt = sdt[i];
    float are = nre * dt, aim = di * dt;
    float e = expf(are); float s, cs; sincosf(aim, &s, &cs);
    float ar = e * cs, ai2 = e * s;
    float xr = bf2f(Xre[base]), xi = bf2f(Xim[base]);
    float nr = ar * hr - ai2 * hi + xr;
    float ni = ar * hi + ai2 * hr + xi;
    hr = nr; hi = ni;
    size_t fb = (size_t)(tok + i) * 512 + d;
    F[fb] = f2bf(hr);
    F[fb + 256] = f2bf(hi);
    base += DD;
  }
}

// ---------------- K3: MFMA GEMM (M=32768, K=512, N=768) + bias/sigmoid epilogue ----------------
__global__ __launch_bounds__(256) void k3_mfma(
    const unsigned short* __restrict__ F,    // [BTOK][512] bf16
    const unsigned short* __restrict__ Wp,   // [768][512] bf16
    const float* __restrict__ bout, const float* __restrict__ bgate,
    float* __restrict__ out)
{
  __shared__ __align__(16) unsigned short As[128 * 32];
  __shared__ __align__(16) unsigned short Bs[128 * 32];
  const int bx = blockIdx.x;
  const int mt = bx & 255, nt = bx >> 8;   // 256 x 6
  const int m0 = mt * 128, n0 = nt * 128;
  const int tid = threadIdx.x;
  const int lane = tid & 63, wid = tid >> 6;
  const int wr = wid >> 1, wc = wid & 1;
  const int l15 = lane & 15, hi8 = (lane >> 4) * 8;
  const int srow = tid >> 2, skof = (tid & 3) * 8;
  f32x4 acc[4][4];
  f32x4 z = {0.f, 0.f, 0.f, 0.f};
#pragma unroll
  for (int i = 0; i < 4; ++i)
#pragma unroll
    for (int j = 0; j < 4; ++j) acc[i][j] = z;

  for (int k0 = 0; k0 < 512; k0 += 32) {
    __syncthreads();
    gl_lds16(&F[(size_t)(m0 + srow) * 512 + k0 + skof], &As[tid * 8]);
    gl_lds16(&F[(size_t)(m0 + 64 + srow) * 512 + k0 + skof], &As[2048 + tid * 8]);
    gl_lds16(&Wp[(size_t)(n0 + srow) * 512 + k0 + skof], &Bs[tid * 8]);
    gl_lds16(&Wp[(size_t)(n0 + 64 + srow) * 512 + k0 + skof], &Bs[2048 + tid * 8]);
    __syncthreads();
    bf16x8 af[4], bfr[4];
#pragma unroll
    for (int m = 0; m < 4; ++m)
      af[m] = *reinterpret_cast<const bf16x8*>(&As[(wr * 64 + m * 16 + l15) * 32 + hi8]);
#pragma unroll
    for (int n = 0; n < 4; ++n)
      bfr[n] = *reinterpret_cast<const bf16x8*>(&Bs[(wc * 64 + n * 16 + l15) * 32 + hi8]);
#pragma unroll
    for (int m = 0; m < 4; ++m)
#pragma unroll
      for (int n = 0; n < 4; ++n)
        acc[m][n] = __builtin_amdgcn_mfma_f32_16x16x32_bf16(af[m], bfr[n], acc[m][n], 0, 0, 0);
  }

  const int nb = n0 + wc * 64;   // wave-uniform: whole wave is src or gate
  if (nb < 512) {
#pragma unroll
    for (int j = 0; j < 4; ++j) {
      const int col = nb + j * 16 + l15;
      const float bb = bout[col];
#pragma unroll
      for (int m = 0; m < 4; ++m)
#pragma unroll
        for (int r = 0; r < 4; ++r) {
          const int row = m0 + wr * 64 + m * 16 + (lane >> 4) * 4 + r;
          out[(size_t)row * 1792 + col] = acc[m][j][r] + bb;
        }
    }
  } else {
#pragma unroll
    for (int j = 0; j < 4; ++j) {
      const int col = nb + j * 16 + l15;
      const float bb = bgate[col - 512];
#pragma unroll
      for (int m = 0; m < 4; ++m)
#pragma unroll
        for (int r = 0; r < 4; ++r) {
          const int row = m0 + wr * 64 + m * 16 + (lane >> 4) * 4 + r;
          float g = 1.f / (1.f + expf(-(acc[m][j][r] + bb)));
          out[(size_t)row * 1792 + col] = g * 0.98f + 0.01f;
        }
    }
  }
}

// ---------------- K4: decay_p / forcing_p planes ----------------
__global__ __launch_bounds__(256) void k4_prop(
    const float* __restrict__ dts, const float* __restrict__ lre,
    const float* __restrict__ lim, float* __restrict__ out)
{
  const int tok = blockIdx.x;
  const int d = threadIdx.x;
  float dt = dts[tok];
  float are = -softplusf(lre[d]) * dt;
  float aim = lim[d] * dt;
  float dr, dm, fr, fm;
  decay_forcing(are, aim, dr, dm, fr, fm);
  float* o = out + (size_t)tok * 1792 + 768;
  o[d] = dr; o[256 + d] = dm; o[512 + d] = fr; o[768 + d] = fm;
}

// ---------------- launch ----------------
extern "C" void kernel_launch(void* const* d_in, const int* in_sizes, int n_in,
                              void* d_out, int out_size, void* d_ws, size_t ws_size,
                              hipStream_t stream)
{
  const float* x     = (const float*)d_in[0];
  const float* dts   = (const float*)d_in[1];
  const float* decr  = (const float*)d_in[2];
  const float* deci  = (const float*)d_in[3];
  const float* Win   = (const float*)d_in[4];
  const float* bin   = (const float*)d_in[5];
  const float* Wout  = (const float*)d_in[6];
  const float* bout  = (const float*)d_in[7];
  const float* Wgate = (const float*)d_in[8];
  const float* bgate = (const float*)d_in[9];
  const float* lre   = (const float*)d_in[10];
  const float* lim   = (const float*)d_in[11];
  float* out = (float*)d_out;
  char* ws = (char*)d_ws;

  // Workspace layout (68 MB):
  //   F   [0, 32MB)      bf16 [BTOK][512] flux packed (written by k2c, read by k3)
  //   Xb  [16MB, 32MB)   bf16 [BTOK][256] x in bf16 — aliases F upper half; dead after k1
  //   Xre [32MB, 48MB)   bf16 [BTOK][256]
  //   Xim [48MB, 64MB)   bf16 [BTOK][256]
  //   Wp1 [64MB, +256KB) bf16 [512][256]
  //   Wp3 [+, +768KB)    bf16 [768][512]
  //   ops [65MB, +2MB)   float4 [8*64*256]
  //   hin [67MB, +1MB)   float2 [8*64*256]
  unsigned short* F   = (unsigned short*)(ws);
  unsigned short* Xb  = (unsigned short*)(ws + (size_t)16 * 1024 * 1024);
  unsigned short* Xre = (unsigned short*)(ws + (size_t)32 * 1024 * 1024);
  unsigned short* Xim = (unsigned short*)(ws + (size_t)48 * 1024 * 1024);
  unsigned short* Wp1 = (unsigned short*)(ws + (size_t)64 * 1024 * 1024);
  unsigned short* Wp3 = (unsigned short*)(ws + (size_t)64 * 1024 * 1024 + 262144);
  float4* ops = (float4*)(ws + (size_t)65 * 1024 * 1024);
  float2* hin = (float2*)(ws + (size_t)67 * 1024 * 1024);

  xcvt<<<8192, 256, 0, stream>>>(x, Xb);   // BTOK*256 elems / (256 thr * 4) = 8192 blocks
  wpack1<<<512, 256, 0, stream>>>(Win, Wp1);
  wpack3<<<768, 256, 0, stream>>>(Wout, Wgate, Wp3);
  k1_mfma<<<1024, 256, 0, stream>>>(Xb, Wp1, bin, dts, decr, deci, Xre, Xim);
  k2a_chunk<<<512, 256, 0, stream>>>(Xre, Xim, dts, decr, deci, ops);
  k2b_carry<<<8, 256, 0, stream>>>(ops, hin);
  k2c_apply<<<512, 256, 0, stream>>>(Xre, Xim, dts, decr, deci, hin, F);
  k3_mfma<<<1536, 256, 0, stream>>>(F, Wp3, bout, bgate, out);
  k4_prop<<<32768, 256, 0, stream>>>(dts, lre, lim, out);
}

// Round 4
// 208.476 us; speedup vs baseline: 3.0713x; 1.0366x over previous
//
#include <hip/hip_runtime.h>
#include <math.h>

// Problem constants
#define DD 256
#define TT 4096
#define NBATCH 8
#define BTOK 32768            // NBATCH*TT tokens
#define EPSF 1e-7f

typedef __attribute__((ext_vector_type(4))) float f32x4;
typedef __attribute__((ext_vector_type(8))) short bf16x8;

// ---------------- helpers ----------------
__device__ __forceinline__ float softplusf(float x) {
  return fmaxf(x, 0.f) + log1pf(expf(-fabsf(x)));
}
__device__ __forceinline__ float bf2f(unsigned short u) {
  union { unsigned int i; float f; } v; v.i = ((unsigned int)u) << 16; return v.f;
}
__device__ __forceinline__ unsigned short f2bf(float f) {  // RTNE
  union { float f; unsigned int i; } v; v.f = f;
  unsigned int x = v.i;
  unsigned int lsb = (x >> 16) & 1u;
  x += 0x7fffu + lsb;
  return (unsigned short)(x >> 16);
}
// decay = exp(are + i*aim); forcing = (decay-1)/(exp_arg + eps*sign(re+eps))
__device__ __forceinline__ void decay_forcing(float are, float aim,
    float& dre, float& dim, float& fre, float& fim) {
  float e = expf(are);
  float s, c; sincosf(aim, &s, &c);
  dre = e * c; dim = e * s;
  float sg = (are + EPSF >= 0.f) ? 1.f : -1.f;
  float denr = are + EPSF * sg;
  float deni = aim;
  float inv = 1.f / (denr * denr + deni * deni);
  float nr = dre - 1.f, ni = dim;
  fre = (nr * denr + ni * deni) * inv;
  fim = (ni * denr - nr * deni) * inv;
}
// async 16B global->LDS (linear dest: wave-uniform base + lane*16)
__device__ __forceinline__ void gl_lds16(const void* g, void* l) {
  __builtin_amdgcn_global_load_lds(
      (const __attribute__((address_space(1))) unsigned int*)g,
      (__attribute__((address_space(3))) unsigned int*)l, 16, 0, 0);
}

// ---------------- prep: fp32 -> bf16 conversions ----------------
// x has BTOK*256 = 8,388,608 floats; each thread converts 4 -> grid 8192.
__global__ __launch_bounds__(256) void xcvt(const float* __restrict__ x,
                                            unsigned short* __restrict__ Xb) {
  size_t i = ((size_t)blockIdx.x * 256 + threadIdx.x) * 4;
  float4 v = *reinterpret_cast<const float4*>(&x[i]);
  ushort4 u;
  u.x = f2bf(v.x); u.y = f2bf(v.y); u.z = f2bf(v.z); u.w = f2bf(v.w);
  *reinterpret_cast<ushort4*>(&Xb[i]) = u;
}

// Pack Win (only k<256 matters; imag input is zero) into [512][256] bf16 with
// re/im rows interleaved in 16-wide groups: row p: g=p>>5, r=p&31,
// src = (r<16) ? g*16+r : 256 + g*16 + (r-16).
__global__ __launch_bounds__(256) void wpack1(const float* __restrict__ Win,
                                              unsigned short* __restrict__ Wp) {
  const int p = blockIdx.x;          // 0..511
  const int k = threadIdx.x;         // 0..255
  const int g = p >> 5, r = p & 31;
  const int src = (r < 16) ? (g * 16 + r) : (256 + g * 16 + (r - 16));
  Wp[(size_t)p * 256 + k] = f2bf(Win[(size_t)src * 512 + k]);
}

// Pack Wout (512 rows) + Wgate (256 rows) into [768][512] bf16.
__global__ __launch_bounds__(256) void wpack3(const float* __restrict__ Wout,
                                              const float* __restrict__ Wgate,
                                              unsigned short* __restrict__ Wp) {
  const int p = blockIdx.x;          // 0..767
  const float* src = (p < 512) ? (Wout + (size_t)p * 512)
                               : (Wgate + (size_t)(p - 512) * 512);
  Wp[(size_t)p * 512 + threadIdx.x] = f2bf(src[threadIdx.x]);
  Wp[(size_t)p * 512 + threadIdx.x + 256] = f2bf(src[threadIdx.x + 256]);
}

// ---------------- K1: MFMA GEMM (M=32768, K=256, N=512 packed) + forcing epilogue ----------------
// Grid 1024 = 256 mt x 4 nt, nt-innermost + bijective XCD swizzle (m204):
// Xb row-panels are shared by the 4 consecutive wgids -> XCD-L2 hits.
__global__ __launch_bounds__(256) void k1_mfma(
    const unsigned short* __restrict__ Xb,   // [BTOK][256] bf16
    const unsigned short* __restrict__ Wp,   // [512][256] bf16 (re/im 16-interleaved)
    const float* __restrict__ bin, const float* __restrict__ dts,
    const float* __restrict__ decr, const float* __restrict__ deci,
    unsigned short* __restrict__ Xre, unsigned short* __restrict__ Xim)
{
  __shared__ __align__(16) unsigned short As[128 * 32];
  __shared__ __align__(16) unsigned short Bs[128 * 32];
  const int bx = blockIdx.x;
  const int wg = (bx & 7) * 128 + (bx >> 3);   // bijective: 1024 = 8 * 128
  const int mt = wg >> 2, nt = wg & 3;
  const int m0 = mt * 128, n0 = nt * 128;
  const int tid = threadIdx.x;
  const int lane = tid & 63, wid = tid >> 6;
  const int wr = wid >> 1, wc = wid & 1;
  const int l15 = lane & 15, hi8 = (lane >> 4) * 8;
  const int srow = tid >> 2, skof = (tid & 3) * 8;
  f32x4 acc[4][4];
  f32x4 z = {0.f, 0.f, 0.f, 0.f};
#pragma unroll
  for (int i = 0; i < 4; ++i)
#pragma unroll
    for (int j = 0; j < 4; ++j) acc[i][j] = z;

  for (int k0 = 0; k0 < 256; k0 += 32) {
    __syncthreads();
    gl_lds16(&Xb[(size_t)(m0 + srow) * 256 + k0 + skof], &As[tid * 8]);
    gl_lds16(&Xb[(size_t)(m0 + 64 + srow) * 256 + k0 + skof], &As[2048 + tid * 8]);
    gl_lds16(&Wp[(size_t)(n0 + srow) * 256 + k0 + skof], &Bs[tid * 8]);
    gl_lds16(&Wp[(size_t)(n0 + 64 + srow) * 256 + k0 + skof], &Bs[2048 + tid * 8]);
    __syncthreads();
    bf16x8 af[4], bfr[4];
#pragma unroll
    for (int m = 0; m < 4; ++m)
      af[m] = *reinterpret_cast<const bf16x8*>(&As[(wr * 64 + m * 16 + l15) * 32 + hi8]);
#pragma unroll
    for (int n = 0; n < 4; ++n)
      bfr[n] = *reinterpret_cast<const bf16x8*>(&Bs[(wc * 64 + n * 16 + l15) * 32 + hi8]);
#pragma unroll
    for (int m = 0; m < 4; ++m)
#pragma unroll
      for (int n = 0; n < 4; ++n)
        acc[m][n] = __builtin_amdgcn_mfma_f32_16x16x32_bf16(af[m], bfr[n], acc[m][n], 0, 0, 0);
  }

  // epilogue: fragment pair (2*pr, 2*pr+1) = (re, im) for same d in same lane
  const int pbase = n0 + wc * 64;
#pragma unroll
  for (int pr = 0; pr < 2; ++pr) {
    const int d = (pbase >> 1) + pr * 16 + l15;
    const float nre = -softplusf(decr[d]);
    const float di = deci[d];
    const float br = bin[d], bi = bin[d + 256];
#pragma unroll
    for (int m = 0; m < 4; ++m) {
#pragma unroll
      for (int r = 0; r < 4; ++r) {
        const int row = m0 + wr * 64 + m * 16 + (lane >> 4) * 4 + r;
        float xr = acc[m][2 * pr][r] + br;
        float xi = acc[m][2 * pr + 1][r] + bi;
        float dt = dts[row];
        float are = nre * dt, aim = di * dt;
        float dr_, dm_, fr_, fm_;
        decay_forcing(are, aim, dr_, dm_, fr_, fm_);
        Xre[(size_t)row * DD + d] = f2bf(xr * fr_ - xi * fm_);
        Xim[(size_t)row * DD + d] = f2bf(xr * fm_ + xi * fr_);
      }
    }
  }
}

// ---------------- K2a: per-chunk scan operators over chunks of 64 steps ----------------
__global__ __launch_bounds__(256) void k2a_chunk(
    const unsigned short* __restrict__ Xre, const unsigned short* __restrict__ Xim,
    const float* __restrict__ dts, const float* __restrict__ decr, const float* __restrict__ deci,
    float4* __restrict__ ops)
{
  const int b = blockIdx.x >> 6;
  const int c = blockIdx.x & 63;
  const int d = threadIdx.x;
  __shared__ float sdt[64];
  if (threadIdx.x < 64) sdt[threadIdx.x] = dts[b * TT + c * 64 + threadIdx.x];
  float nre = -softplusf(decr[d]);
  float di = deci[d];
  __syncthreads();
  float Ar = 1.f, Ai = 0.f, Br2 = 0.f, Bi2 = 0.f;
  size_t base = (size_t)(b * TT + c * 64) * DD + d;
  for (int i = 0; i < 64; ++i) {
    float dt = sdt[i];
    float are = nre * dt, aim = di * dt;
    float e = expf(are); float s, cs; sincosf(aim, &s, &cs);
    float ar = e * cs, ai2 = e * s;
    float xr = bf2f(Xre[base]), xi = bf2f(Xim[base]);
    base += DD;
    float nAr = Ar * ar - Ai * ai2;
    float nAi = Ar * ai2 + Ai * ar;
    Ar = nAr; Ai = nAi;
    float nBr = Br2 * ar - Bi2 * ai2 + xr;
    float nBi = Br2 * ai2 + Bi2 * ar + xi;
    Br2 = nBr; Bi2 = nBi;
  }
  ops[(size_t)(b * 64 + c) * DD + d] = make_float4(Ar, Ai, Br2, Bi2);
}

// ---------------- K2b: carry scan across 64 chunks per channel (8-deep prefetch) ----------------
__global__ __launch_bounds__(256) void k2b_carry(
    const float4* __restrict__ ops, float2* __restrict__ hin)
{
  const int b = blockIdx.x;
  const int d = threadIdx.x;
  float hr = 0.f, hi = 0.f;
  const size_t base = (size_t)b * 64 * DD + d;
  for (int c0 = 0; c0 < 64; c0 += 8) {
    // 8 independent loads issued before the dependent carry chain
    float4 o0 = ops[base + (size_t)(c0 + 0) * DD];
    float4 o1 = ops[base + (size_t)(c0 + 1) * DD];
    float4 o2 = ops[base + (size_t)(c0 + 2) * DD];
    float4 o3 = ops[base + (size_t)(c0 + 3) * DD];
    float4 o4 = ops[base + (size_t)(c0 + 4) * DD];
    float4 o5 = ops[base + (size_t)(c0 + 5) * DD];
    float4 o6 = ops[base + (size_t)(c0 + 6) * DD];
    float4 o7 = ops[base + (size_t)(c0 + 7) * DD];
    float4 oo[8] = {o0, o1, o2, o3, o4, o5, o6, o7};
#pragma unroll
    for (int j = 0; j < 8; ++j) {
      hin[base + (size_t)(c0 + j) * DD] = make_float2(hr, hi);
      float nr = oo[j].x * hr - oo[j].y * hi + oo[j].z;
      float ni = oo[j].x * hi + oo[j].y * hr + oo[j].w;
      hr = nr; hi = ni;
    }
  }
}

// ---------------- K2c: apply; store flux packed [token][512] bf16 (re | im) ----------------
__global__ __launch_bounds__(256) void k2c_apply(
    const unsigned short* __restrict__ Xre, const unsigned short* __restrict__ Xim,
    const float* __restrict__ dts, const float* __restrict__ decr, const float* __restrict__ deci,
    const float2* __restrict__ hin,
    unsigned short* __restrict__ F)
{
  const int b = blockIdx.x >> 6;
  const int c = blockIdx.x & 63;
  const int d = threadIdx.x;
  __shared__ float sdt[64];
  if (threadIdx.x < 64) sdt[threadIdx.x] = dts[b * TT + c * 64 + threadIdx.x];
  float nre = -softplusf(decr[d]);
  float di = deci[d];
  __syncthreads();
  float2 h = hin[(size_t)(b * 64 + c) * DD + d];
  float hr = h.x, hi = h.y;
  int tok = b * TT + c * 64;
  size_t base = (size_t)tok * DD + d;
  for (int i = 0; i < 64; ++i) {
    float dt = sdt[i];
    float are = nre * dt, aim = di * dt;
    float e = expf(are); float s, cs; sincosf(aim, &s, &cs);
    float ar = e * cs, ai2 = e * s;
    float xr = bf2f(Xre[base]), xi = bf2f(Xim[base]);
    float nr = ar * hr - ai2 * hi + xr;
    float ni = ar * hi + ai2 * hr + xi;
    hr = nr; hi = ni;
    size_t fb = (size_t)(tok + i) * 512 + d;
    F[fb] = f2bf(hr);
    F[fb + 256] = f2bf(hi);
    base += DD;
  }
}

// ---------------- K3: MFMA GEMM (M=32768, K=512, N=768) + bias/sigmoid epilogue ----------------
// Grid 1536 = 256 mt x 6 nt, nt-innermost + bijective XCD swizzle: the 6 blocks
// sharing one F row-panel (128 KB) run adjacently on one XCD -> L2 hits instead
// of 6x HBM/L3 re-fetch of F (192 MB -> ~32 MB).
__global__ __launch_bounds__(256) void k3_mfma(
    const unsigned short* __restrict__ F,    // [BTOK][512] bf16
    const unsigned short* __restrict__ Wp,   // [768][512] bf16
    const float* __restrict__ bout, const float* __restrict__ bgate,
    float* __restrict__ out)
{
  __shared__ __align__(16) unsigned short As[128 * 32];
  __shared__ __align__(16) unsigned short Bs[128 * 32];
  const int bx = blockIdx.x;
  const int wg = (bx & 7) * 192 + (bx >> 3);   // bijective: 1536 = 8 * 192
  const int mt = wg / 6, nt = wg % 6;
  const int m0 = mt * 128, n0 = nt * 128;
  const int tid = threadIdx.x;
  const int lane = tid & 63, wid = tid >> 6;
  const int wr = wid >> 1, wc = wid & 1;
  const int l15 = lane & 15, hi8 = (lane >> 4) * 8;
  const int srow = tid >> 2, skof = (tid & 3) * 8;
  f32x4 acc[4][4];
  f32x4 z = {0.f, 0.f, 0.f, 0.f};
#pragma unroll
  for (int i = 0; i < 4; ++i)
#pragma unroll
    for (int j = 0; j < 4; ++j) acc[i][j] = z;

  for (int k0 = 0; k0 < 512; k0 += 32) {
    __syncthreads();
    gl_lds16(&F[(size_t)(m0 + srow) * 512 + k0 + skof], &As[tid * 8]);
    gl_lds16(&F[(size_t)(m0 + 64 + srow) * 512 + k0 + skof], &As[2048 + tid * 8]);
    gl_lds16(&Wp[(size_t)(n0 + srow) * 512 + k0 + skof], &Bs[tid * 8]);
    gl_lds16(&Wp[(size_t)(n0 + 64 + srow) * 512 + k0 + skof], &Bs[2048 + tid * 8]);
    __syncthreads();
    bf16x8 af[4], bfr[4];
#pragma unroll
    for (int m = 0; m < 4; ++m)
      af[m] = *reinterpret_cast<const bf16x8*>(&As[(wr * 64 + m * 16 + l15) * 32 + hi8]);
#pragma unroll
    for (int n = 0; n < 4; ++n)
      bfr[n] = *reinterpret_cast<const bf16x8*>(&Bs[(wc * 64 + n * 16 + l15) * 32 + hi8]);
#pragma unroll
    for (int m = 0; m < 4; ++m)
#pragma unroll
      for (int n = 0; n < 4; ++n)
        acc[m][n] = __builtin_amdgcn_mfma_f32_16x16x32_bf16(af[m], bfr[n], acc[m][n], 0, 0, 0);
  }

  const int nb = n0 + wc * 64;   // wave-uniform: whole wave is src or gate
  if (nb < 512) {
#pragma unroll
    for (int j = 0; j < 4; ++j) {
      const int col = nb + j * 16 + l15;
      const float bb = bout[col];
#pragma unroll
      for (int m = 0; m < 4; ++m)
#pragma unroll
        for (int r = 0; r < 4; ++r) {
          const int row = m0 + wr * 64 + m * 16 + (lane >> 4) * 4 + r;
          out[(size_t)row * 1792 + col] = acc[m][j][r] + bb;
        }
    }
  } else {
#pragma unroll
    for (int j = 0; j < 4; ++j) {
      const int col = nb + j * 16 + l15;
      const float bb = bgate[col - 512];
#pragma unroll
      for (int m = 0; m < 4; ++m)
#pragma unroll
        for (int r = 0; r < 4; ++r) {
          const int row = m0 + wr * 64 + m * 16 + (lane >> 4) * 4 + r;
          float g = 1.f / (1.f + expf(-(acc[m][j][r] + bb)));
          out[(size_t)row * 1792 + col] = g * 0.98f + 0.01f;
        }
    }
  }
}

// ---------------- K4: decay_p / forcing_p planes ----------------
__global__ __launch_bounds__(256) void k4_prop(
    const float* __restrict__ dts, const float* __restrict__ lre,
    const float* __restrict__ lim, float* __restrict__ out)
{
  const int tok = blockIdx.x;
  const int d = threadIdx.x;
  float dt = dts[tok];
  float are = -softplusf(lre[d]) * dt;
  float aim = lim[d] * dt;
  float dr, dm, fr, fm;
  decay_forcing(are, aim, dr, dm, fr, fm);
  float* o = out + (size_t)tok * 1792 + 768;
  o[d] = dr; o[256 + d] = dm; o[512 + d] = fr; o[768 + d] = fm;
}

// ---------------- launch ----------------
extern "C" void kernel_launch(void* const* d_in, const int* in_sizes, int n_in,
                              void* d_out, int out_size, void* d_ws, size_t ws_size,
                              hipStream_t stream)
{
  const float* x     = (const float*)d_in[0];
  const float* dts   = (const float*)d_in[1];
  const float* decr  = (const float*)d_in[2];
  const float* deci  = (const float*)d_in[3];
  const float* Win   = (const float*)d_in[4];
  const float* bin   = (const float*)d_in[5];
  const float* Wout  = (const float*)d_in[6];
  const float* bout  = (const float*)d_in[7];
  const float* Wgate = (const float*)d_in[8];
  const float* bgate = (const float*)d_in[9];
  const float* lre   = (const float*)d_in[10];
  const float* lim   = (const float*)d_in[11];
  float* out = (float*)d_out;
  char* ws = (char*)d_ws;

  // Workspace layout (68 MB):
  //   F   [0, 32MB)      bf16 [BTOK][512] flux packed (written by k2c, read by k3)
  //   Xb  [16MB, 32MB)   bf16 [BTOK][256] x in bf16 — aliases F upper half; dead after k1
  //   Xre [32MB, 48MB)   bf16 [BTOK][256]
  //   Xim [48MB, 64MB)   bf16 [BTOK][256]
  //   Wp1 [64MB, +256KB) bf16 [512][256]
  //   Wp3 [+, +768KB)    bf16 [768][512]
  //   ops [65MB, +2MB)   float4 [8*64*256]
  //   hin [67MB, +1MB)   float2 [8*64*256]
  unsigned short* F   = (unsigned short*)(ws);
  unsigned short* Xb  = (unsigned short*)(ws + (size_t)16 * 1024 * 1024);
  unsigned short* Xre = (unsigned short*)(ws + (size_t)32 * 1024 * 1024);
  unsigned short* Xim = (unsigned short*)(ws + (size_t)48 * 1024 * 1024);
  unsigned short* Wp1 = (unsigned short*)(ws + (size_t)64 * 1024 * 1024);
  unsigned short* Wp3 = (unsigned short*)(ws + (size_t)64 * 1024 * 1024 + 262144);
  float4* ops = (float4*)(ws + (size_t)65 * 1024 * 1024);
  float2* hin = (float2*)(ws + (size_t)67 * 1024 * 1024);

  xcvt<<<8192, 256, 0, stream>>>(x, Xb);   // BTOK*256 elems / (256 thr * 4) = 8192 blocks
  wpack1<<<512, 256, 0, stream>>>(Win, Wp1);
  wpack3<<<768, 256, 0, stream>>>(Wout, Wgate, Wp3);
  k1_mfma<<<1024, 256, 0, stream>>>(Xb, Wp1, bin, dts, decr, deci, Xre, Xim);
  k2a_chunk<<<512, 256, 0, stream>>>(Xre, Xim, dts, decr, deci, ops);
  k2b_carry<<<8, 256, 0, stream>>>(ops, hin);
  k2c_apply<<<512, 256, 0, stream>>>(Xre, Xim, dts, decr, deci, hin, F);
  k3_mfma<<<1536, 256, 0, stream>>>(F, Wp3, bout, bgate, out);
  k4_prop<<<32768, 256, 0, stream>>>(dts, lre, lim, out);
}